// Round 14
// baseline (126.659 us; speedup 1.0000x reference)
//
#include <hip/hip_runtime.h>
#include <hip/hip_bf16.h>
#include <math.h>

#define B_DIM 8192
#define IN_F  1024
#define OUT_F 1024
#define NSTEP 160                    // 32 g-groups x 5 slabs (K=5120)
#define BTILE 8192                   // one step-tile: 128 rows/cols x 32 k x 2B

typedef unsigned short u16;
typedef unsigned int u32;
typedef __attribute__((ext_vector_type(8))) short bf16x8;
typedef __attribute__((ext_vector_type(8))) unsigned short u16x8;
typedef __attribute__((ext_vector_type(4))) float f32x4;

#define GLOBAL_AS __attribute__((address_space(1)))
#define LDS_AS    __attribute__((address_space(3)))

__device__ __forceinline__ void gload16(const void* g, void* l) {
    __builtin_amdgcn_global_load_lds((const GLOBAL_AS unsigned int*)g,
                                     (LDS_AS unsigned int*)l, 16, 0, 0);
}

__device__ __forceinline__ u16 f2bf(float v) {
    u32 u = __float_as_uint(v);
    return (u16)((u + 0x7FFFu + ((u >> 16) & 1u)) >> 16);
}

__device__ __forceinline__ u32 cvt_pk(float lo, float hi) {
    u32 r;
    asm("v_cvt_pk_bf16_f32 %0, %1, %2" : "=v"(r) : "v"(lo), "v"(hi));
    return r;
}

// x-space step threshold for grid value gv: smallest f32 T with
// (x >= T) <=> ((double)x > atanh(midpoint(gv, prevfloat(gv)))) —
// replicates a correctly-rounded tanh's interval comparisons.
__device__ __forceinline__ float step_threshold(float gv) {
    float below = nextafterf(gv, -2.0f);
    double mid = 0.5 * ((double)gv + (double)below);
    double t = atanh(mid);
    float Tf = (float)t;
    if (!((double)Tf > t)) Tf = nextafterf(Tf, 3.0f);
    return Tf;
}

// ---------------------------------------------------------------------------
// prep kernel — one launch, three sections by blockIdx (R13, unchanged):
//   bid 0..511    : pack_B  (s=0 base_weight, s=1..4 bf16(sw_s - sw_{s-1}))
//   bid 512..767  : bias[o] = sum_i sw[o,i,0]
//   bid 768..4863 : pack_A  (s=0 bf16(x), s=1..4 indicators 1[x >= T_s])
// Tile byte = ((panel*160 + t)*8192) + sub*1024 + lane*16 for both images.
// ---------------------------------------------------------------------------
__global__ __launch_bounds__(256) void prep_kernel(
    const float* __restrict__ x, const float* __restrict__ sw,
    const float* __restrict__ bw, const float* __restrict__ grid,
    char* __restrict__ At, char* __restrict__ Bt, float* __restrict__ biasT)
{
    int bid = blockIdx.x;
    int tid = threadIdx.x;

    if (bid < 512) {                                // ---- pack_B ----
        int gid  = bid * 256 + tid;
        int lane = gid & 63;
        int wav  = gid >> 6;
        int g    = wav & 31;
        int sn   = (wav >> 5) & 7;
        int p    = wav >> 8;                        // 0..7
        int fc   = lane & 15;
        int q    = lane >> 4;

        int o  = p * 128 + sn * 16 + fc;
        int i0 = g * 32 + q * 8;

        size_t tb = ((size_t)(p * NSTEP + g * 5)) * BTILE
                  + (size_t)sn * 1024 + (size_t)lane * 16;

        const float* bwr = bw + (size_t)o * IN_F + i0;
        float4 b0 = *(const float4*)bwr;
        float4 b1 = *(const float4*)(bwr + 4);
        float v[8] = {b0.x, b0.y, b0.z, b0.w, b1.x, b1.y, b1.z, b1.w};
        u16x8 s0;
        #pragma unroll
        for (int j = 0; j < 8; ++j) s0[j] = f2bf(v[j]);
        *(u16x8*)(Bt + tb) = s0;                    // s = 0

        float c[8][5];
        #pragma unroll
        for (int j = 0; j < 8; ++j) {
            const float* swr = sw + ((size_t)o * IN_F + i0 + j) * 8;
            float4 lo = *(const float4*)swr;
            float4 hi = *(const float4*)(swr + 4);
            c[j][0] = lo.x; c[j][1] = lo.y; c[j][2] = lo.z;
            c[j][3] = lo.w; c[j][4] = hi.x;
        }
        #pragma unroll
        for (int s = 1; s < 5; ++s) {
            u16x8 d;
            #pragma unroll
            for (int j = 0; j < 8; ++j) d[j] = f2bf(c[j][s] - c[j][s - 1]);
            *(u16x8*)(Bt + tb + (size_t)s * BTILE) = d;
        }
    } else if (bid < 768) {                         // ---- bias ----
        int o    = (bid - 512) * 4 + (tid >> 6);
        int lane = tid & 63;
        float s = 0.f;
        #pragma unroll
        for (int j = 0; j < 16; ++j)
            s += sw[((size_t)o * IN_F + j * 64 + lane) * 8];
        #pragma unroll
        for (int off = 32; off; off >>= 1)
            s += __shfl_down(s, off);
        if (lane == 0) biasT[o] = s;
    } else {                                        // ---- pack_A ----
        __shared__ float thr[4];
        if (tid == 0) {
            #pragma unroll
            for (int k = 0; k < 4; ++k)
                thr[k] = step_threshold(grid[k + 1]);   // -0.6,-0.2,0.2,0.6
        }
        __syncthreads();
        float T1 = thr[0], T2 = thr[1], T3 = thr[2], T4 = thr[3];

        int gid  = (bid - 768) * 256 + tid;         // 0 .. 1,048,575
        int lane = gid & 63;
        int wav  = gid >> 6;
        int g    = wav & 31;
        int sm   = (wav >> 5) & 7;
        int p    = wav >> 8;                        // 0..63
        int fr   = lane & 15;
        int q    = lane >> 4;

        int b  = p * 128 + sm * 16 + fr;
        int i0 = g * 32 + q * 8;

        const float* xr = x + (size_t)b * IN_F + i0;
        float4 a0 = *(const float4*)xr;
        float4 a1 = *(const float4*)(xr + 4);
        float v[8] = {a0.x, a0.y, a0.z, a0.w, a1.x, a1.y, a1.z, a1.w};

        size_t tb = ((size_t)(p * NSTEP + g * 5)) * BTILE
                  + (size_t)sm * 1024 + (size_t)lane * 16;

        {
            union { u32 u[4]; u16x8 s; } wpk;
            #pragma unroll
            for (int j = 0; j < 4; ++j) wpk.u[j] = cvt_pk(v[2*j], v[2*j+1]);
            *(u16x8*)(At + tb) = wpk.s;             // s = 0: bf16(x)
        }
        float T[4] = {T1, T2, T3, T4};
        #pragma unroll
        for (int s = 0; s < 4; ++s) {
            union { u32 u[4]; u16x8 t; } o;
            #pragma unroll
            for (int j = 0; j < 4; ++j)
                o.u[j] = (v[2*j]     >= T[s] ? 0x00003F80u : 0u)
                       | (v[2*j + 1] >= T[s] ? 0x3F800000u : 0u);
            *(u16x8*)(At + tb + (size_t)(s + 1) * BTILE) = o.t;
        }
    }
}

// ---------------------------------------------------------------------------
// GEMM: C = A @ B^T + bias. 128x128 tile, 160 step-tiles of BK=32.
// A: 4-slot LDS ring via global_load_lds (depth-3 issue).
// B: fragments direct global->register, single-buffered — B panel is
//    1.31 MB/XCD (L2-resident); each bf[n] is a coalesced dwordx4/lane.
// LDS traffic per CU-round: 48 KB (was 96) -> under the ~85 B/cyc
// ds_read ceiling (m134) that capped R11 at 85 us.
// Per tile: barrier -> bf loads -> stage A(t+3) -> af ds_reads ->
// vmcnt(2) (FIFO: drains bf + old stages, leaves A(t+3)) -> 16 MFMA.
// 4 waves 2x2; wave = 64x64 out = 4x4 frags of 16x16.
// ---------------------------------------------------------------------------
#define WAITV(N) asm volatile("s_waitcnt vmcnt(" #N ")" ::: "memory")

__global__ __launch_bounds__(256, 2) void gemm_kernel(
    const char* __restrict__ At, const char* __restrict__ Bt,
    const float* __restrict__ biasT, float* __restrict__ C)
{
    __shared__ __align__(16) char lds[4 * BTILE];   // A-only ring, 32 KB

    int tid = threadIdx.x;
    int bid = blockIdx.x;                           // 0..511

    // XCD swizzle: each XCD owns 8 brow-panels x all 8 bcols -> A-panel
    // shared by 8 same-XCD blocks (L2 reuse; FETCH=82MB proves it).
    int xcd  = bid & 7;
    int slot = bid >> 3;
    int tile = xcd * 64 + slot;
    int brow = tile >> 3;                           // 0..63
    int bcol = tile & 7;                            // 0..7

    int lane = tid & 63;
    int w    = tid >> 6;
    int wr   = w >> 1;
    int wc   = w & 1;

    const char* Ap = At + (size_t)brow * NSTEP * BTILE;
    const char* Bw = Bt + (size_t)bcol * NSTEP * BTILE
                   + (size_t)(wc * 4) * 1024 + (size_t)lane * 16;

    int ccol0 = bcol * 128 + wc * 64 + (lane & 15);

    f32x4 acc[4][4];
    #pragma unroll
    for (int n = 0; n < 4; ++n) {
        float bv = biasT[ccol0 + n * 16];
        #pragma unroll
        for (int m = 0; m < 4; ++m)
            #pragma unroll
            for (int j = 0; j < 4; ++j)
                acc[m][n][j] = bv;
    }

    #define STAGE_A(T) do {                                                   \
        const char* _s = Ap + (size_t)(T) * BTILE;                            \
        char* _d = lds + ((T) & 3) * BTILE;                                   \
        gload16(_s + tid * 16,        _d + tid * 16);                         \
        gload16(_s + tid * 16 + 4096, _d + tid * 16 + 4096);                  \
    } while (0)

    // one tile: barrier publishes A(t); bf issued BEFORE newest stage so
    // vmcnt(WN) covers them without draining A(t+3).
    #define TILE_STEP(T, DOSTAGE, WN) do {                                    \
        __builtin_amdgcn_s_barrier();                                         \
        asm volatile("" ::: "memory");                                        \
        const char* _bp = Bw + (size_t)(T) * BTILE;                           \
        bf16x8 bf0 = *(const bf16x8*)(_bp);                                   \
        bf16x8 bf1 = *(const bf16x8*)(_bp + 1024);                            \
        bf16x8 bf2 = *(const bf16x8*)(_bp + 2048);                            \
        bf16x8 bf3 = *(const bf16x8*)(_bp + 3072);                            \
        if (DOSTAGE) STAGE_A((T) + 3);                                        \
        const u16* _as = (const u16*)(lds + ((T) & 3) * BTILE);               \
        bf16x8 af[4];                                                         \
        _Pragma("unroll")                                                     \
        for (int _m = 0; _m < 4; ++_m)                                        \
            af[_m] = *(const bf16x8*)(_as + (wr * 4 + _m) * 512 + lane * 8);  \
        WAITV(WN);                                                            \
        __builtin_amdgcn_sched_barrier(0);                                    \
        __builtin_amdgcn_s_setprio(1);                                        \
        _Pragma("unroll")                                                     \
        for (int _m = 0; _m < 4; ++_m) {                                      \
            acc[_m][0] = __builtin_amdgcn_mfma_f32_16x16x32_bf16(af[_m], bf0, acc[_m][0], 0, 0, 0); \
            acc[_m][1] = __builtin_amdgcn_mfma_f32_16x16x32_bf16(af[_m], bf1, acc[_m][1], 0, 0, 0); \
            acc[_m][2] = __builtin_amdgcn_mfma_f32_16x16x32_bf16(af[_m], bf2, acc[_m][2], 0, 0, 0); \
            acc[_m][3] = __builtin_amdgcn_mfma_f32_16x16x32_bf16(af[_m], bf3, acc[_m][3], 0, 0, 0); \
        }                                                                     \
        __builtin_amdgcn_s_setprio(0);                                        \
    } while (0)

    // prologue: stage A(0..2); drain A(0),A(1) -> invariant: A(t+2) in flight
    STAGE_A(0); STAGE_A(1); STAGE_A(2);
    WAITV(2);

    #pragma unroll 1
    for (int t = 0; t < 157; ++t)
        TILE_STEP(t, 1, 2);                         // stages A(3..159)

    TILE_STEP(157, 0, 0);
    TILE_STEP(158, 0, 0);
    TILE_STEP(159, 0, 0);

    #undef TILE_STEP
    #undef STAGE_A

    // epilogue: C/D layout col = lane&15, row = (lane>>4)*4 + reg (bias in acc)
    int crow0 = brow * 128 + wr * 64 + ((lane >> 4) << 2);
    #pragma unroll
    for (int m = 0; m < 4; ++m)
        #pragma unroll
        for (int j = 0; j < 4; ++j) {
            size_t r = (size_t)(crow0 + m * 16 + j);
            float* cp = C + r * OUT_F + ccol0;
            #pragma unroll
            for (int n = 0; n < 4; ++n)
                cp[n * 16] = acc[m][n][j];
        }
}

// Fallback signal if workspace is too small: absmax will read ~12345.
__global__ void sentinel_kernel(float* out, int n) {
    int i = blockIdx.x * 256 + threadIdx.x;
    if (i < n) out[i] = (i == 0) ? 12345.0f : 0.0f;
}

extern "C" void kernel_launch(void* const* d_in, const int* in_sizes, int n_in,
                              void* d_out, int out_size, void* d_ws, size_t ws_size,
                              hipStream_t stream) {
    const float* x    = (const float*)d_in[0];
    const float* sw   = (const float*)d_in[1];
    const float* bw   = (const float*)d_in[2];
    const float* grid = (const float*)d_in[3];
    float* out = (float*)d_out;

    const size_t A_bytes = (size_t)64 * NSTEP * BTILE;  // 83,886,080
    const size_t B_bytes = (size_t)8  * NSTEP * BTILE;  // 10,485,760
    const size_t bias_bytes = 1024 * sizeof(float);
    if (ws_size < A_bytes + B_bytes + bias_bytes) {
        sentinel_kernel<<<(out_size + 255) / 256, 256, 0, stream>>>(out, out_size);
        return;
    }

    char*  At    = (char*)d_ws;
    char*  Bt    = (char*)d_ws + A_bytes;
    float* biasT = (float*)((char*)d_ws + A_bytes + B_bytes);

    prep_kernel<<<4864, 256, 0, stream>>>(x, sw, bw, grid, At, Bt, biasT);
    gemm_kernel<<<512, 256, 0, stream>>>(At, Bt, biasT, out);
}

// Round 15
// 115.863 us; speedup vs baseline: 1.0932x; 1.0932x over previous
//
#include <hip/hip_runtime.h>
#include <hip/hip_bf16.h>
#include <math.h>

#define B_DIM 8192
#define IN_F  1024
#define OUT_F 1024
#define NSTEP 160                    // 32 g-groups x 5 slabs (K=5120)
#define TILEB 16384                  // one step-tile: 256 rows/cols x 32 k x 2B
#define NT    80                     // K-tiles per half (K-split 2)

typedef unsigned short u16;
typedef unsigned int u32;
typedef __attribute__((ext_vector_type(8))) short bf16x8;
typedef __attribute__((ext_vector_type(8))) unsigned short u16x8;
typedef __attribute__((ext_vector_type(4))) float f32x4;

#define GLOBAL_AS __attribute__((address_space(1)))
#define LDS_AS    __attribute__((address_space(3)))

__device__ __forceinline__ void gload16(const void* g, void* l) {
    __builtin_amdgcn_global_load_lds((const GLOBAL_AS unsigned int*)g,
                                     (LDS_AS unsigned int*)l, 16, 0, 0);
}

__device__ __forceinline__ u16 f2bf(float v) {
    u32 u = __float_as_uint(v);
    return (u16)((u + 0x7FFFu + ((u >> 16) & 1u)) >> 16);
}

__device__ __forceinline__ u32 cvt_pk(float lo, float hi) {
    u32 r;
    asm("v_cvt_pk_bf16_f32 %0, %1, %2" : "=v"(r) : "v"(lo), "v"(hi));
    return r;
}

// x-space step threshold for grid value gv: smallest f32 T with
// (x >= T) <=> ((double)x > atanh(midpoint(gv, prevfloat(gv)))) —
// replicates a correctly-rounded tanh's interval comparisons.
__device__ __forceinline__ float step_threshold(float gv) {
    float below = nextafterf(gv, -2.0f);
    double mid = 0.5 * ((double)gv + (double)below);
    double t = atanh(mid);
    float Tf = (float)t;
    if (!((double)Tf > t)) Tf = nextafterf(Tf, 3.0f);
    return Tf;
}

// ---------------------------------------------------------------------------
// prep kernel — one launch, three sections by blockIdx:
//   bid 0..511    : pack_B  (4 panels x 256 cols; s=0 base_weight,
//                   s=1..4 bf16(sw_s - sw_{s-1}); tiles t = g*5 + s)
//   bid 512..767  : bias[o] = sum_i sw[o,i,0]
//   bid 768..4863 : pack_A  (32 panels x 256 rows; s=0 bf16(x),
//                   s=1..4 indicators 1[x >= T_s])
// Tile byte = ((panel*160 + t)*16384) + sub*1024 + lane*16 for both images.
// ---------------------------------------------------------------------------
__global__ __launch_bounds__(256) void prep_kernel(
    const float* __restrict__ x, const float* __restrict__ sw,
    const float* __restrict__ bw, const float* __restrict__ grid,
    char* __restrict__ At, char* __restrict__ Bt, float* __restrict__ biasT)
{
    int bid = blockIdx.x;
    int tid = threadIdx.x;

    if (bid < 512) {                                // ---- pack_B ----
        int gid  = bid * 256 + tid;
        int lane = gid & 63;
        int wav  = gid >> 6;                        // 0..2047
        int g    = wav & 31;
        int sn   = (wav >> 5) & 15;
        int p    = wav >> 9;                        // 0..3
        int fc   = lane & 15;
        int q    = lane >> 4;

        int o  = p * 256 + sn * 16 + fc;
        int i0 = g * 32 + q * 8;

        size_t tb = ((size_t)(p * NSTEP + g * 5)) * TILEB
                  + (size_t)sn * 1024 + (size_t)lane * 16;

        const float* bwr = bw + (size_t)o * IN_F + i0;
        float4 b0 = *(const float4*)bwr;
        float4 b1 = *(const float4*)(bwr + 4);
        float v[8] = {b0.x, b0.y, b0.z, b0.w, b1.x, b1.y, b1.z, b1.w};
        u16x8 s0;
        #pragma unroll
        for (int j = 0; j < 8; ++j) s0[j] = f2bf(v[j]);
        *(u16x8*)(Bt + tb) = s0;                    // s = 0

        float c[8][5];
        #pragma unroll
        for (int j = 0; j < 8; ++j) {
            const float* swr = sw + ((size_t)o * IN_F + i0 + j) * 8;
            float4 lo = *(const float4*)swr;
            float4 hi = *(const float4*)(swr + 4);
            c[j][0] = lo.x; c[j][1] = lo.y; c[j][2] = lo.z;
            c[j][3] = lo.w; c[j][4] = hi.x;
        }
        #pragma unroll
        for (int s = 1; s < 5; ++s) {
            u16x8 d;
            #pragma unroll
            for (int j = 0; j < 8; ++j) d[j] = f2bf(c[j][s] - c[j][s - 1]);
            *(u16x8*)(Bt + tb + (size_t)s * TILEB) = d;
        }
    } else if (bid < 768) {                         // ---- bias ----
        int o    = (bid - 512) * 4 + (tid >> 6);
        int lane = tid & 63;
        float s = 0.f;
        #pragma unroll
        for (int j = 0; j < 16; ++j)
            s += sw[((size_t)o * IN_F + j * 64 + lane) * 8];
        #pragma unroll
        for (int off = 32; off; off >>= 1)
            s += __shfl_down(s, off);
        if (lane == 0) biasT[o] = s;
    } else {                                        // ---- pack_A ----
        __shared__ float thr[4];
        if (tid == 0) {
            #pragma unroll
            for (int k = 0; k < 4; ++k)
                thr[k] = step_threshold(grid[k + 1]);   // -0.6,-0.2,0.2,0.6
        }
        __syncthreads();
        float T1 = thr[0], T2 = thr[1], T3 = thr[2], T4 = thr[3];

        int gid  = (bid - 768) * 256 + tid;         // 0 .. 1,048,575
        int lane = gid & 63;
        int wav  = gid >> 6;                        // 0..16383
        int g    = wav & 31;
        int sm   = (wav >> 5) & 15;
        int p    = wav >> 9;                        // 0..31
        int fr   = lane & 15;
        int q    = lane >> 4;

        int b  = p * 256 + sm * 16 + fr;
        int i0 = g * 32 + q * 8;

        const float* xr = x + (size_t)b * IN_F + i0;
        float4 a0 = *(const float4*)xr;
        float4 a1 = *(const float4*)(xr + 4);
        float v[8] = {a0.x, a0.y, a0.z, a0.w, a1.x, a1.y, a1.z, a1.w};

        size_t tb = ((size_t)(p * NSTEP + g * 5)) * TILEB
                  + (size_t)sm * 1024 + (size_t)lane * 16;

        {
            union { u32 u[4]; u16x8 s; } wpk;
            #pragma unroll
            for (int j = 0; j < 4; ++j) wpk.u[j] = cvt_pk(v[2*j], v[2*j+1]);
            *(u16x8*)(At + tb) = wpk.s;             // s = 0: bf16(x)
        }
        float T[4] = {T1, T2, T3, T4};
        #pragma unroll
        for (int s = 0; s < 4; ++s) {
            union { u32 u[4]; u16x8 t; } o;
            #pragma unroll
            for (int j = 0; j < 4; ++j)
                o.u[j] = (v[2*j]     >= T[s] ? 0x00003F80u : 0u)
                       | (v[2*j + 1] >= T[s] ? 0x3F800000u : 0u);
            *(u16x8*)(At + tb + (size_t)(s + 1) * TILEB) = o.t;
        }
    }
}

// ---------------------------------------------------------------------------
// GEMM half: 256x256 output tile, K-split 2 (80 step-tiles of BK=32 each).
// Grid 256 = 32 brow x 4 bcol x 2 kh -> 1 block/CU. 512 threads = 8 waves
// (2 row-halves x 4 col-quarters); wave = 128x64 out = 8x4 frags, 32 MFMA
// per tile per wave (375 B LDS-read/MFMA vs R11's 512).
// 4-slot x 32KB LDS ring, R11's exact counted-vmcnt schedule (4 ops/tile,
// WAITV 8/4/0, one barrier per tile, depth-3 prefetch, setprio on MFMA).
// kh=0 writes out (+bias); kh=1 writes bf16 partial to p1.
// Launch-index swizzle: the 4 bcol-siblings of each (brow,kh) share an XCD.
// ---------------------------------------------------------------------------
#define WAITV(N) asm volatile("s_waitcnt vmcnt(" #N ")" ::: "memory")

__global__ __launch_bounds__(512, 2) void gemm_half_kernel(
    const char* __restrict__ At, const char* __restrict__ Bt,
    const float* __restrict__ biasT, float* __restrict__ out,
    u16* __restrict__ p1)
{
    __shared__ __align__(16) char lds[4 * 32768];   // 128 KB ring

    int tid = threadIdx.x;
    int bid = blockIdx.x;                           // 0..255

    int xcd = bid & 7;
    int r   = bid >> 3;                             // 0..31
    int bcol = r & 3;
    int gh  = r >> 2;                               // 0..7
    int g   = (gh << 3) | xcd;                      // 0..63
    int brow = g >> 1;                              // 0..31
    int kh  = g & 1;                                // K half

    int lane = tid & 63;
    int w    = tid >> 6;                            // 0..7
    int wr   = w >> 2;                              // row half (128 rows)
    int wc   = w & 3;                               // col quarter (64 cols)
    int fr   = lane & 15;
    int q    = lane >> 4;

    const char* Ap = At + ((size_t)brow * NSTEP + (size_t)kh * NT) * TILEB;
    const char* Bp = Bt + ((size_t)bcol * NSTEP + (size_t)kh * NT) * TILEB;

    f32x4 acc[8][4];
    #pragma unroll
    for (int m = 0; m < 8; ++m)
        #pragma unroll
        for (int n = 0; n < 4; ++n)
            #pragma unroll
            for (int j = 0; j < 4; ++j)
                acc[m][n][j] = 0.0f;

    #define STAGE(T) do {                                                     \
        const char* _sa = Ap + (size_t)(T) * TILEB;                           \
        const char* _sb = Bp + (size_t)(T) * TILEB;                           \
        char* _d = lds + ((T) & 3) * 32768;                                   \
        gload16(_sa + tid * 16,        _d + tid * 16);                        \
        gload16(_sa + tid * 16 + 8192, _d + tid * 16 + 8192);                 \
        gload16(_sb + tid * 16,        _d + 16384 + tid * 16);                \
        gload16(_sb + tid * 16 + 8192, _d + 16384 + tid * 16 + 8192);         \
    } while (0)

    // prologue: 3 tiles staged, 12 loads in flight
    STAGE(0); STAGE(1); STAGE(2);

    #pragma unroll 1
    for (int t = 0; t < NT; ++t) {
        if (t < NT - 2)       WAITV(8);             // drains tile t only
        else if (t == NT - 2) WAITV(4);
        else                  WAITV(0);
        __builtin_amdgcn_s_barrier();               // publish stage(t)
        asm volatile("" ::: "memory");

        if (t + 3 < NT) STAGE(t + 3);

        const char* slot = lds + (t & 3) * 32768;
        bf16x8 af[8], bf[4];
        #pragma unroll
        for (int m = 0; m < 8; ++m)
            af[m] = *(const bf16x8*)(slot + (wr * 8 + m) * 1024 + lane * 16);
        #pragma unroll
        for (int n = 0; n < 4; ++n)
            bf[n] = *(const bf16x8*)(slot + 16384 + (wc * 4 + n) * 1024 + lane * 16);

        __builtin_amdgcn_s_setprio(1);
        #pragma unroll
        for (int m = 0; m < 8; ++m)
            #pragma unroll
            for (int n = 0; n < 4; ++n)
                acc[m][n] = __builtin_amdgcn_mfma_f32_16x16x32_bf16(
                    af[m], bf[n], acc[m][n], 0, 0, 0);
        __builtin_amdgcn_s_setprio(0);
    }
    #undef STAGE

    // epilogue: C/D layout col = lane&15, row = (lane>>4)*4 + reg
    int crow0 = brow * 256 + wr * 128 + (q << 2);
    int ccol0 = bcol * 256 + wc * 64 + fr;
    if (kh == 0) {
        float bv[4];
        #pragma unroll
        for (int n = 0; n < 4; ++n) bv[n] = biasT[ccol0 + n * 16];
        #pragma unroll
        for (int m = 0; m < 8; ++m)
            #pragma unroll
            for (int j = 0; j < 4; ++j) {
                size_t rr = (size_t)(crow0 + m * 16 + j);
                float* cp = out + rr * OUT_F + ccol0;
                #pragma unroll
                for (int n = 0; n < 4; ++n)
                    cp[n * 16] = acc[m][n][j] + bv[n];
            }
    } else {
        #pragma unroll
        for (int m = 0; m < 8; ++m)
            #pragma unroll
            for (int j = 0; j < 4; ++j) {
                size_t rr = (size_t)(crow0 + m * 16 + j);
                u16* cp = p1 + rr * OUT_F + ccol0;
                #pragma unroll
                for (int n = 0; n < 4; ++n)
                    cp[n * 16] = f2bf(acc[m][n][j]);
            }
    }
}

// ---------------------------------------------------------------------------
// reduce: out += f32(p1)   (8 elems/thread, vectorized)
// ---------------------------------------------------------------------------
__global__ __launch_bounds__(256) void reduce_kernel(
    float* __restrict__ out, const u16* __restrict__ p1)
{
    int i = (blockIdx.x * 256 + threadIdx.x) * 8;
    u16x8 pv = *(const u16x8*)(p1 + i);
    float4 a0 = *(const float4*)(out + i);
    float4 a1 = *(const float4*)(out + i + 4);
    float av[8] = {a0.x, a0.y, a0.z, a0.w, a1.x, a1.y, a1.z, a1.w};
    #pragma unroll
    for (int j = 0; j < 8; ++j)
        av[j] += __uint_as_float(((u32)pv[j]) << 16);
    float4 r0 = {av[0], av[1], av[2], av[3]};
    float4 r1 = {av[4], av[5], av[6], av[7]};
    *(float4*)(out + i)     = r0;
    *(float4*)(out + i + 4) = r1;
}

// Fallback signal if workspace is too small: absmax will read ~12345.
__global__ void sentinel_kernel(float* out, int n) {
    int i = blockIdx.x * 256 + threadIdx.x;
    if (i < n) out[i] = (i == 0) ? 12345.0f : 0.0f;
}

extern "C" void kernel_launch(void* const* d_in, const int* in_sizes, int n_in,
                              void* d_out, int out_size, void* d_ws, size_t ws_size,
                              hipStream_t stream) {
    const float* x    = (const float*)d_in[0];
    const float* sw   = (const float*)d_in[1];
    const float* bw   = (const float*)d_in[2];
    const float* grid = (const float*)d_in[3];
    float* out = (float*)d_out;

    const size_t A_bytes  = (size_t)32 * NSTEP * TILEB;     // 83,886,080
    const size_t B_bytes  = (size_t)4  * NSTEP * TILEB;     // 10,485,760
    const size_t p1_bytes = (size_t)B_DIM * OUT_F * 2;      // 16,777,216
    const size_t bias_bytes = 1024 * sizeof(float);
    if (ws_size < A_bytes + B_bytes + p1_bytes + bias_bytes) {
        sentinel_kernel<<<(out_size + 255) / 256, 256, 0, stream>>>(out, out_size);
        return;
    }

    char*  At    = (char*)d_ws;
    char*  Bt    = (char*)d_ws + A_bytes;
    u16*   p1    = (u16*)((char*)d_ws + A_bytes + B_bytes);
    float* biasT = (float*)((char*)d_ws + A_bytes + B_bytes + p1_bytes);

    prep_kernel<<<4864, 256, 0, stream>>>(x, sw, bw, grid, At, Bt, biasT);
    gemm_half_kernel<<<256, 512, 0, stream>>>(At, Bt, biasT, out, p1);
    reduce_kernel<<<B_DIM * OUT_F / 2048, 256, 0, stream>>>(out, p1);
}